// Round 16
// baseline (83.934 us; speedup 1.0000x reference)
//
#include <hip/hip_runtime.h>
#include <hip/hip_bf16.h>
#include <stdint.h>

typedef __bf16 bf16_t;
typedef __bf16 v8bf  __attribute__((ext_vector_type(8)));
typedef __bf16 v4bf  __attribute__((ext_vector_type(4)));
typedef float  f32x4 __attribute__((ext_vector_type(4)));
typedef unsigned short u16x8 __attribute__((ext_vector_type(8)));

#define B_   2
#define T_   2048
#define D_   768
#define H_   12
#define DH_  64
#define N3_  2304
#define M_   4096

// async global->LDS, 16B per lane; LDS dest must be wave-uniform base (HW adds lane*16)
__device__ __forceinline__ void gll16(const void* g, void* l) {
  __builtin_amdgcn_global_load_lds(
      (const __attribute__((address_space(1))) void*)g,
      (__attribute__((address_space(3))) void*)l,
      16, 0, 0);
}

__device__ __forceinline__ float bf2f(unsigned short u) {
  union { unsigned u; float f; } x; x.u = ((unsigned)u) << 16; return x.f;
}

// ---------------- 1. convert x: fp32 -> bf16 ----------------
__global__ __launch_bounds__(256) void k_conv_x(const float* __restrict__ x,
                                                bf16_t* __restrict__ xb, int n4) {
  int i = blockIdx.x * 256 + threadIdx.x;
  if (i < n4) {
    float4 v = ((const float4*)x)[i];
    v4bf o = {(bf16_t)v.x, (bf16_t)v.y, (bf16_t)v.z, (bf16_t)v.w};
    *(v4bf*)(xb + (size_t)i * 4) = o;
  }
}

// ---------------- 2. convert + transpose W: [768,2304] fp32 -> Wt [2304,768] bf16 ----
__global__ __launch_bounds__(256) void k_conv_wt(const float* __restrict__ W,
                                                 bf16_t* __restrict__ Wt) {
  __shared__ bf16_t tile[64 * 64];
  const int tid = threadIdx.x;
  const int n0 = blockIdx.x * 64;   // col tile of W (row of Wt), 36 tiles
  const int k0 = blockIdx.y * 64;   // row tile of W, 12 tiles
  #pragma unroll
  for (int rr = 0; rr < 4; ++rr) {
    int k  = rr * 16 + (tid >> 4);
    int gr = tid & 15;
    float4 v = *(const float4*)(W + (size_t)(k0 + k) * N3_ + n0 + gr * 4);
    v4bf o = {(bf16_t)v.x, (bf16_t)v.y, (bf16_t)v.z, (bf16_t)v.w};
    *(v4bf*)(tile + k * 64 + ((gr ^ (k & 15)) << 2)) = o;
  }
  __syncthreads();
  const int n = tid & 63, q = tid >> 6;
  bf16_t outv[16] __attribute__((aligned(16)));
  #pragma unroll
  for (int tt = 0; tt < 16; ++tt) {
    int k = q * 16 + tt;
    outv[tt] = tile[k * 64 + (((n >> 2) ^ (k & 15)) << 2) + (n & 3)];
  }
  bf16_t* dst = Wt + (size_t)(n0 + n) * D_ + k0 + q * 16;
  *(u16x8*)dst       = *(const u16x8*)outv;
  *((u16x8*)dst + 1) = *(const u16x8*)(outv + 8);
}

// ---------------- 3. GEMM: qkv = xb @ Wt^T + bias; V blocks write Vt directly ----
// Same serial-staging structure as R11 (2-barrier, gll16 width 16 — untouched),
// but 128x64 tiles: grid (36,32) = 1152 blocks = 4.5/CU (vs 576 = 2.25/CU),
// fixing the 3-vs-2 blocks/CU tail imbalance and improving cross-block overlap.
// Waves: 2M x 2N, wave tile 64x32, acc[4][2]. LDS 12KB.
// Q columns (n < 768) pre-scaled by DH^-0.5 * log2(e); V columns (n >= 1536)
// written transposed+column-permuted to vt so attention's P stays in-register.
#define BK 32
__global__ __launch_bounds__(256) void k_gemm(const bf16_t* __restrict__ A,   // [4096,768]
                                              const bf16_t* __restrict__ Bt,  // [2304,768]
                                              const float*  __restrict__ bias,
                                              bf16_t* __restrict__ Cq,        // [4096,2304]
                                              bf16_t* __restrict__ vt) {      // [24,64,2048]
  __shared__ bf16_t As[128 * BK];   // 8 KB
  __shared__ bf16_t Bs[64 * BK];    // 4 KB
  const int tid  = threadIdx.x;
  const int wave = tid >> 6, lane = tid & 63;
  const int g = lane >> 4, c = lane & 15;
  const int wy = wave >> 1, wx = wave & 1;     // M-half, N-half
  const int bm = blockIdx.y * 128, bn = blockIdx.x * 64;

  const f32x4 zf = {0.f, 0.f, 0.f, 0.f};
  f32x4 acc[4][2];
  #pragma unroll
  for (int i = 0; i < 4; ++i)
    #pragma unroll
    for (int j = 0; j < 2; ++j) acc[i][j] = zf;

  const int rA = tid >> 2;          // row within 64-row half-tile
  const int kc = (tid & 3) * 8;     // k-element within BK

  for (int k0 = 0; k0 < D_; k0 += BK) {
    __syncthreads();
    #pragma unroll
    for (int cc = 0; cc < 2; ++cc)
      gll16(A + (size_t)(bm + cc * 64 + rA) * D_ + k0 + kc,
            (char*)As + cc * 4096 + wave * 1024);
    gll16(Bt + (size_t)(bn + rA) * D_ + k0 + kc,
          (char*)Bs + wave * 1024);
    __syncthreads();
    v8bf af[4], bfr[2];
    #pragma unroll
    for (int mi = 0; mi < 4; ++mi)
      af[mi] = *(const v8bf*)(As + (wy * 64 + mi * 16 + c) * BK + g * 8);
    #pragma unroll
    for (int ni = 0; ni < 2; ++ni)
      bfr[ni] = *(const v8bf*)(Bs + (wx * 32 + ni * 16 + c) * BK + g * 8);
    #pragma unroll
    for (int mi = 0; mi < 4; ++mi)
      #pragma unroll
      for (int ni = 0; ni < 2; ++ni)
        acc[mi][ni] = __builtin_amdgcn_mfma_f32_16x16x32_bf16(af[mi], bfr[ni], acc[mi][ni], 0, 0, 0);
  }

  if (bn >= 2 * D_) {
    // V block (one head per tile): transposed + column-permuted store into vt
    const int hb = (bn - 2 * D_) >> 6;                 // head, block-uniform
    #pragma unroll
    for (int ni = 0; ni < 2; ++ni) {
      float bv = bias[bn + wx * 32 + ni * 16 + c];
      const int d = wx * 32 + ni * 16 + c;
      #pragma unroll
      for (int mi = 0; mi < 4; ++mi) {
        int row = bm + wy * 64 + mi * 16 + g * 4;      // global row (t), 4-aligned
        int b = row >> 11, t = row & (T_ - 1);
        int tl = t & 63;
        // s = [b5=kk | b4b3=g | b2=ih | b1b0=j] from t = [kk|ih|g|j]
        int sp = (t & ~63) | (tl & 35) | ((tl & 12) << 1) | ((tl & 16) >> 2);
        v4bf o = {(bf16_t)(acc[mi][ni][0] + bv), (bf16_t)(acc[mi][ni][1] + bv),
                  (bf16_t)(acc[mi][ni][2] + bv), (bf16_t)(acc[mi][ni][3] + bv)};
        *(v4bf*)(vt + ((size_t)((b * H_ + hb) * DH_ + d)) * T_ + sp) = o;
      }
    }
  } else {
    // Q/K block: Q columns get softmax scale folded in (768 % 64 == 0)
    const float qscale = (bn < D_) ? 0.18033688011112042f : 1.0f;  // 0.125 * log2(e)
    #pragma unroll
    for (int ni = 0; ni < 2; ++ni) {
      float bv = bias[bn + wx * 32 + ni * 16 + c];
      #pragma unroll
      for (int mi = 0; mi < 4; ++mi) {
        int row = bm + wy * 64 + mi * 16 + g * 4;
        bf16_t* d0 = Cq + (size_t)row * N3_ + bn + wx * 32 + ni * 16 + c;
        #pragma unroll
        for (int j = 0; j < 4; ++j)
          d0[(size_t)j * N3_] = (bf16_t)((acc[mi][ni][j] + bv) * qscale);
      }
    }
  }
}

// ---------------- 5. flash attention: P in-register, dbuf K/V, 1 barrier/tile ------
// R11/R15 kernel, byte-identical (confirmed best: 43.5us, MfmaUtil 24, 0 conflicts).
template<int SPLIT>
__global__ __launch_bounds__(256) void k_attn(const bf16_t* __restrict__ qkv,
                                              const bf16_t* __restrict__ vt,
                                              float* __restrict__ outp,
                                              float* __restrict__ lpart) {
  __shared__ __align__(16) bf16_t Ks[2][64 * 64];   // K tile, rows=key, XOR-swizzled
  __shared__ __align__(16) bf16_t Vs[2][64 * 64];   // V^T tile (pre-permuted cols)
  const int tid  = threadIdx.x;
  const int wave = tid >> 6, lane = tid & 63;
  const int g = lane >> 4, c = lane & 15;
  const int qt = blockIdx.x;           // 32 q-tiles of 64 rows
  const int bh = blockIdx.y;           // 24
  const int z  = (SPLIT > 1) ? blockIdx.z : 0;
  const int b = bh / H_, h = bh - b * H_;
  const int r0 = z * (T_ / SPLIT);     // key-range base

  // hoisted Q fragments: lane holds Q[q = c][d = 8g..8g+7 (+32)] (pre-scaled)
  v8bf aq[2];
  {
    const bf16_t* qb = qkv + ((size_t)(b * T_ + qt * 64 + wave * 16 + c)) * N3_ + h * DH_ + g * 8;
    aq[0] = *(const v8bf*)qb;
    aq[1] = *(const v8bf*)(qb + 32);
  }
  float lsum = 0.f;
  const f32x4 zf = {0.f, 0.f, 0.f, 0.f};
  f32x4 oacc[4];                            // O^T[d = ni*16+g*4+j][q = c]
  #pragma unroll
  for (int ni = 0; ni < 4; ++ni) oacc[ni] = zf;

  // staging pointers (pre-swizzled global source, linear LDS dest — rule #21)
  const int rS  = tid >> 3;   // 0..31
  const int grS = tid & 7;
  const bf16_t* gK[2];
  const bf16_t* gV[2];
  #pragma unroll
  for (int cc = 0; cc < 2; ++cc) {
    int r    = cc * 32 + rS;
    int colk = ((grS ^ (r & 7)) << 3);
    gK[cc] = qkv + ((size_t)(b * T_ + r0 + r)) * N3_ + D_ + h * DH_ + colk;
    gV[cc] = vt + ((size_t)(bh * DH_ + r)) * T_ + r0 + colk;
  }

  // prologue: stage tile 0 into buf 0
  #pragma unroll
  for (int cc = 0; cc < 2; ++cc) {
    gll16(gK[cc], (char*)Ks[0] + cc * 4096 + wave * 1024);
    gll16(gV[cc], (char*)Vs[0] + cc * 4096 + wave * 1024);
    gK[cc] += 64 * (size_t)N3_;
    gV[cc] += 64;
  }
  __syncthreads();

#define ATTN_BODY(CUR, NXT, DOSTAGE)                                          \
  {                                                                           \
    if (DOSTAGE) {                                                            \
      _Pragma("unroll")                                                       \
      for (int cc = 0; cc < 2; ++cc) {                                        \
        gll16(gK[cc], (char*)Ks[NXT] + cc * 4096 + wave * 1024);              \
        gll16(gV[cc], (char*)Vs[NXT] + cc * 4096 + wave * 1024);              \
        gK[cc] += 64 * (size_t)N3_;                                           \
        gV[cc] += 64;                                                         \
      }                                                                       \
    }                                                                         \
    f32x4 s[4] = {zf, zf, zf, zf};                                            \
    __builtin_amdgcn_s_setprio(1);                                            \
    _Pragma("unroll")                                                         \
    for (int kk = 0; kk < 2; ++kk) {                                          \
      _Pragma("unroll")                                                       \
      for (int ni = 0; ni < 4; ++ni) {                                        \
        const int row = ni * 16 + c;                                          \
        v8bf bk = *(const v8bf*)(Ks[CUR] + row * 64 +                         \
                                 ((kk * 32 + g * 8) ^ ((row & 7) << 3)));     \
        s[ni] = __builtin_amdgcn_mfma_f32_16x16x32_bf16(bk, aq[kk], s[ni], 0, 0, 0); \
      }                                                                       \
    }                                                                         \
    __builtin_amdgcn_s_setprio(0);                                            \
    float rsub = 0.f;                                                         \
    v8bf apk[2];                                                              \
    _Pragma("unroll")                                                         \
    for (int ni = 0; ni < 4; ++ni) {                                          \
      float p0 = __builtin_amdgcn_exp2f(s[ni][0]);                            \
      float p1 = __builtin_amdgcn_exp2f(s[ni][1]);                            \
      float p2 = __builtin_amdgcn_exp2f(s[ni][2]);                            \
      float p3 = __builtin_amdgcn_exp2f(s[ni][3]);                            \
      rsub += (p0 + p1) + (p2 + p3);                                          \
      const int kkh = ni >> 1, off = (ni & 1) * 4;                            \
      apk[kkh][off + 0] = (bf16_t)p0;                                         \
      apk[kkh][off + 1] = (bf16_t)p1;                                         \
      apk[kkh][off + 2] = (bf16_t)p2;                                         \
      apk[kkh][off + 3] = (bf16_t)p3;                                         \
    }                                                                         \
    lsum += rsub;                                                             \
    __builtin_amdgcn_s_setprio(1);                                            \
    _Pragma("unroll")                                                         \
    for (int kk = 0; kk < 2; ++kk) {                                          \
      _Pragma("unroll")                                                       \
      for (int ni = 0; ni < 4; ++ni) {                                        \
        const int row = ni * 16 + c;                                          \
        v8bf bv = *(const v8bf*)(Vs[CUR] + row * 64 +                         \
                                 ((kk * 32 + g * 8) ^ ((row & 7) << 3)));     \
        oacc[ni] = __builtin_amdgcn_mfma_f32_16x16x32_bf16(bv, apk[kk], oacc[ni], 0, 0, 0); \
      }                                                                       \
    }                                                                         \
    __builtin_amdgcn_s_setprio(0);                                            \
    __syncthreads();                                                          \
  }

  // NT tiles, unrolled x2 with static buffer indices
  const int NT2 = T_ / (64 * SPLIT * 2);
  for (int kt2 = 0; kt2 < NT2; ++kt2) {
    ATTN_BODY(0, 1, true)
    ATTN_BODY(1, 0, (kt2 < NT2 - 1))
  }
#undef ATTN_BODY

  // epilogue
  lsum += __shfl_xor(lsum, 16);
  lsum += __shfl_xor(lsum, 32);
  const float inv = 1.0f / lsum;
  const int q = qt * 64 + wave * 16 + c;
  if (SPLIT > 1) {
    if (g == 0) lpart[(size_t)z * (B_ * H_ * T_) + (b * H_ + h) * T_ + q] = lsum;
    bf16_t* ob = (bf16_t*)outp + ((size_t)z * M_ * D_ + ((size_t)(b * T_ + q)) * D_ + h * DH_);
    #pragma unroll
    for (int ni = 0; ni < 4; ++ni) {
      v4bf o4 = {(bf16_t)(oacc[ni][0] * inv), (bf16_t)(oacc[ni][1] * inv),
                 (bf16_t)(oacc[ni][2] * inv), (bf16_t)(oacc[ni][3] * inv)};
      *(v4bf*)(ob + ni * 16 + g * 4) = o4;
    }
  } else {
    float* ob = outp + ((size_t)(b * T_ + q)) * D_ + h * DH_;
    #pragma unroll
    for (int ni = 0; ni < 4; ++ni) {
      float4 o4 = {oacc[ni][0] * inv, oacc[ni][1] * inv, oacc[ni][2] * inv, oacc[ni][3] * inv};
      *(float4*)(ob + ni * 16 + g * 4) = o4;
    }
  }
}

extern "C" void kernel_launch(void* const* d_in, const int* in_sizes, int n_in,
                              void* d_out, int out_size, void* d_ws, size_t ws_size,
                              hipStream_t stream) {
  const float* x    = (const float*)d_in[0];
  const float* W    = (const float*)d_in[1];
  const float* bias = (const float*)d_in[2];
  float* out = (float*)d_out;
  char* ws = (char*)d_ws;
  bf16_t* xb    = (bf16_t*)(ws);                 // 4096*768*2   = 6,291,456
  bf16_t* wt    = (bf16_t*)(ws + 6291456);       // 2304*768*2   = 3,538,944
  bf16_t* qkvb  = (bf16_t*)(ws + 9830400);       // 4096*2304*2  = 18,874,368
  bf16_t* vtb   = (bf16_t*)(ws + 28704768);      // 24*64*2048*2 = 6,291,456

  k_conv_x <<<dim3(3072),    dim3(256), 0, stream>>>(x, xb, (M_ * D_) / 4);
  k_conv_wt<<<dim3(36, 12),  dim3(256), 0, stream>>>(W, wt);
  k_gemm   <<<dim3(36, 32),  dim3(256), 0, stream>>>(xb, wt, bias, qkvb, vtb);
  k_attn<1><<<dim3(32, 24),  dim3(256), 0, stream>>>(qkvb, vtb, out, nullptr);
}

// Round 17
// 73.204 us; speedup vs baseline: 1.1466x; 1.1466x over previous
//
#include <hip/hip_runtime.h>
#include <hip/hip_bf16.h>
#include <stdint.h>

typedef __bf16 bf16_t;
typedef __bf16 v8bf  __attribute__((ext_vector_type(8)));
typedef __bf16 v4bf  __attribute__((ext_vector_type(4)));
typedef float  f32x4 __attribute__((ext_vector_type(4)));
typedef unsigned short u16x8 __attribute__((ext_vector_type(8)));

#define B_   2
#define T_   2048
#define D_   768
#define H_   12
#define DH_  64
#define N3_  2304
#define M_   4096

// async global->LDS, 16B per lane; LDS dest must be wave-uniform base (HW adds lane*16)
__device__ __forceinline__ void gll16(const void* g, void* l) {
  __builtin_amdgcn_global_load_lds(
      (const __attribute__((address_space(1))) void*)g,
      (__attribute__((address_space(3))) void*)l,
      16, 0, 0);
}

__device__ __forceinline__ float bf2f(unsigned short u) {
  union { unsigned u; float f; } x; x.u = ((unsigned)u) << 16; return x.f;
}

// ---------------- 1+2 fused: x fp32->bf16 (blocks [0,3072)) and
//                  W [768,2304] fp32 -> Wt [2304,768] bf16 (blocks [3072,3504)) ----
__global__ __launch_bounds__(256) void k_conv(const float* __restrict__ x,
                                              bf16_t* __restrict__ xb,
                                              const float* __restrict__ W,
                                              bf16_t* __restrict__ Wt) {
  __shared__ bf16_t tile[64 * 64];
  const int tid = threadIdx.x;
  int bid = blockIdx.x;
  if (bid < 3072) {
    // conv_x: 3072*256 == M_*D_/4 exactly, no bounds check needed
    int i = bid * 256 + tid;
    float4 v = ((const float4*)x)[i];
    v4bf o = {(bf16_t)v.x, (bf16_t)v.y, (bf16_t)v.z, (bf16_t)v.w};
    *(v4bf*)(xb + (size_t)i * 4) = o;
    return;
  }
  bid -= 3072;                      // 432 blocks: 36 n-tiles x 12 k-tiles
  const int n0 = (bid % 36) * 64;   // col tile of W (row of Wt)
  const int k0 = (bid / 36) * 64;   // row tile of W
  #pragma unroll
  for (int rr = 0; rr < 4; ++rr) {
    int k  = rr * 16 + (tid >> 4);
    int gr = tid & 15;
    float4 v = *(const float4*)(W + (size_t)(k0 + k) * N3_ + n0 + gr * 4);
    v4bf o = {(bf16_t)v.x, (bf16_t)v.y, (bf16_t)v.z, (bf16_t)v.w};
    *(v4bf*)(tile + k * 64 + ((gr ^ (k & 15)) << 2)) = o;
  }
  __syncthreads();
  const int n = tid & 63, q = tid >> 6;
  bf16_t outv[16] __attribute__((aligned(16)));
  #pragma unroll
  for (int tt = 0; tt < 16; ++tt) {
    int k = q * 16 + tt;
    outv[tt] = tile[k * 64 + (((n >> 2) ^ (k & 15)) << 2) + (n & 3)];
  }
  bf16_t* dst = Wt + (size_t)(n0 + n) * D_ + k0 + q * 16;
  *(u16x8*)dst       = *(const u16x8*)outv;
  *((u16x8*)dst + 1) = *(const u16x8*)(outv + 8);
}

// ---------------- 3. GEMM: qkv = xb @ Wt^T + bias; V blocks write Vt directly ----
// R11-proven serial-staging structure (BK=32, 128x128 tile, 576 blocks) — verified
// optimum after 4 refuted variants (dbuf, BK64, 128x64). Do not touch.
// Q columns (n < 768) pre-scaled by DH^-0.5 * log2(e); V columns (n >= 1536)
// written transposed+column-permuted to vt so attention's P stays in-register.
#define BK 32
__global__ __launch_bounds__(256) void k_gemm(const bf16_t* __restrict__ A,   // [4096,768]
                                              const bf16_t* __restrict__ Bt,  // [2304,768]
                                              const float*  __restrict__ bias,
                                              bf16_t* __restrict__ Cq,        // [4096,2304]
                                              bf16_t* __restrict__ vt) {      // [24,64,2048]
  __shared__ bf16_t As[128 * BK];
  __shared__ bf16_t Bs[128 * BK];
  const int tid  = threadIdx.x;
  const int wave = tid >> 6, lane = tid & 63;
  const int g = lane >> 4, c = lane & 15;
  const int wy = wave >> 1, wx = wave & 1;
  const int bm = blockIdx.y * 128, bn = blockIdx.x * 128;

  const f32x4 zf = {0.f, 0.f, 0.f, 0.f};
  f32x4 acc[4][4];
  #pragma unroll
  for (int i = 0; i < 4; ++i)
    #pragma unroll
    for (int j = 0; j < 4; ++j) acc[i][j] = zf;

  const int rA = tid >> 2;          // row within 64-row half-tile
  const int kc = (tid & 3) * 8;     // k-element within BK

  for (int k0 = 0; k0 < D_; k0 += BK) {
    __syncthreads();
    #pragma unroll
    for (int cc = 0; cc < 2; ++cc) {
      gll16(A  + (size_t)(bm + cc * 64 + rA) * D_ + k0 + kc,
            (char*)As + cc * 4096 + wave * 1024);
      gll16(Bt + (size_t)(bn + cc * 64 + rA) * D_ + k0 + kc,
            (char*)Bs + cc * 4096 + wave * 1024);
    }
    __syncthreads();
    v8bf af[4], bfr[4];
    #pragma unroll
    for (int mi = 0; mi < 4; ++mi)
      af[mi] = *(const v8bf*)(As + (wy * 64 + mi * 16 + c) * BK + g * 8);
    #pragma unroll
    for (int ni = 0; ni < 4; ++ni)
      bfr[ni] = *(const v8bf*)(Bs + (wx * 64 + ni * 16 + c) * BK + g * 8);
    #pragma unroll
    for (int mi = 0; mi < 4; ++mi)
      #pragma unroll
      for (int ni = 0; ni < 4; ++ni)
        acc[mi][ni] = __builtin_amdgcn_mfma_f32_16x16x32_bf16(af[mi], bfr[ni], acc[mi][ni], 0, 0, 0);
  }

  if (bn >= 2 * D_) {
    // V block: write transposed + column-permuted into vt (4-elem granule kept)
    const int hb = ((bn - 2 * D_) >> 6) + wx;          // head, block/wave-uniform
    #pragma unroll
    for (int ni = 0; ni < 4; ++ni) {
      float bv = bias[bn + wx * 64 + ni * 16 + c];
      const int d = ni * 16 + c;
      #pragma unroll
      for (int mi = 0; mi < 4; ++mi) {
        int row = bm + wy * 64 + mi * 16 + g * 4;      // global row, 4-aligned
        int b = row >> 11, t = row & (T_ - 1);
        int tl = t & 63;
        // s = [b5=kk | b4b3=g | b2=ih | b1b0=j] from t = [kk|ih|g|j]
        int sp = (t & ~63) | (tl & 35) | ((tl & 12) << 1) | ((tl & 16) >> 2);
        v4bf o = {(bf16_t)(acc[mi][ni][0] + bv), (bf16_t)(acc[mi][ni][1] + bv),
                  (bf16_t)(acc[mi][ni][2] + bv), (bf16_t)(acc[mi][ni][3] + bv)};
        *(v4bf*)(vt + ((size_t)((b * H_ + hb) * DH_ + d)) * T_ + sp) = o;
      }
    }
  } else {
    // Q/K block: Q columns get softmax scale folded in (768 % 128 == 0)
    const float qscale = (bn < D_) ? 0.18033688011112042f : 1.0f;  // 0.125 * log2(e)
    #pragma unroll
    for (int ni = 0; ni < 4; ++ni) {
      float bv = bias[bn + wx * 64 + ni * 16 + c];
      #pragma unroll
      for (int mi = 0; mi < 4; ++mi) {
        int row = bm + wy * 64 + mi * 16 + g * 4;
        bf16_t* d0 = Cq + (size_t)row * N3_ + bn + wx * 64 + ni * 16 + c;
        #pragma unroll
        for (int j = 0; j < 4; ++j)
          d0[(size_t)j * N3_] = (bf16_t)((acc[mi][ni][j] + bv) * qscale);
      }
    }
  }
}

// ---------------- 5. flash attention: P in-register, dbuf K/V, 1 barrier/tile ------
// R11/R15 kernel, byte-identical (confirmed best: 43.5us, MfmaUtil 24, 0 conflicts).
template<int SPLIT>
__global__ __launch_bounds__(256) void k_attn(const bf16_t* __restrict__ qkv,
                                              const bf16_t* __restrict__ vt,
                                              float* __restrict__ outp,
                                              float* __restrict__ lpart) {
  __shared__ __align__(16) bf16_t Ks[2][64 * 64];   // K tile, rows=key, XOR-swizzled
  __shared__ __align__(16) bf16_t Vs[2][64 * 64];   // V^T tile (pre-permuted cols)
  const int tid  = threadIdx.x;
  const int wave = tid >> 6, lane = tid & 63;
  const int g = lane >> 4, c = lane & 15;
  const int qt = blockIdx.x;           // 32 q-tiles of 64 rows
  const int bh = blockIdx.y;           // 24
  const int z  = (SPLIT > 1) ? blockIdx.z : 0;
  const int b = bh / H_, h = bh - b * H_;
  const int r0 = z * (T_ / SPLIT);     // key-range base

  // hoisted Q fragments: lane holds Q[q = c][d = 8g..8g+7 (+32)] (pre-scaled)
  v8bf aq[2];
  {
    const bf16_t* qb = qkv + ((size_t)(b * T_ + qt * 64 + wave * 16 + c)) * N3_ + h * DH_ + g * 8;
    aq[0] = *(const v8bf*)qb;
    aq[1] = *(const v8bf*)(qb + 32);
  }
  float lsum = 0.f;
  const f32x4 zf = {0.f, 0.f, 0.f, 0.f};
  f32x4 oacc[4];                            // O^T[d = ni*16+g*4+j][q = c]
  #pragma unroll
  for (int ni = 0; ni < 4; ++ni) oacc[ni] = zf;

  // staging pointers (pre-swizzled global source, linear LDS dest — rule #21)
  const int rS  = tid >> 3;   // 0..31
  const int grS = tid & 7;
  const bf16_t* gK[2];
  const bf16_t* gV[2];
  #pragma unroll
  for (int cc = 0; cc < 2; ++cc) {
    int r    = cc * 32 + rS;
    int colk = ((grS ^ (r & 7)) << 3);
    gK[cc] = qkv + ((size_t)(b * T_ + r0 + r)) * N3_ + D_ + h * DH_ + colk;
    gV[cc] = vt + ((size_t)(bh * DH_ + r)) * T_ + r0 + colk;
  }

  // prologue: stage tile 0 into buf 0
  #pragma unroll
  for (int cc = 0; cc < 2; ++cc) {
    gll16(gK[cc], (char*)Ks[0] + cc * 4096 + wave * 1024);
    gll16(gV[cc], (char*)Vs[0] + cc * 4096 + wave * 1024);
    gK[cc] += 64 * (size_t)N3_;
    gV[cc] += 64;
  }
  __syncthreads();

#define ATTN_BODY(CUR, NXT, DOSTAGE)                                          \
  {                                                                           \
    if (DOSTAGE) {                                                            \
      _Pragma("unroll")                                                       \
      for (int cc = 0; cc < 2; ++cc) {                                        \
        gll16(gK[cc], (char*)Ks[NXT] + cc * 4096 + wave * 1024);              \
        gll16(gV[cc], (char*)Vs[NXT] + cc * 4096 + wave * 1024);              \
        gK[cc] += 64 * (size_t)N3_;                                           \
        gV[cc] += 64;                                                         \
      }                                                                       \
    }                                                                         \
    f32x4 s[4] = {zf, zf, zf, zf};                                            \
    __builtin_amdgcn_s_setprio(1);                                            \
    _Pragma("unroll")                                                         \
    for (int kk = 0; kk < 2; ++kk) {                                          \
      _Pragma("unroll")                                                       \
      for (int ni = 0; ni < 4; ++ni) {                                        \
        const int row = ni * 16 + c;                                          \
        v8bf bk = *(const v8bf*)(Ks[CUR] + row * 64 +                         \
                                 ((kk * 32 + g * 8) ^ ((row & 7) << 3)));     \
        s[ni] = __builtin_amdgcn_mfma_f32_16x16x32_bf16(bk, aq[kk], s[ni], 0, 0, 0); \
      }                                                                       \
    }                                                                         \
    __builtin_amdgcn_s_setprio(0);                                            \
    float rsub = 0.f;                                                         \
    v8bf apk[2];                                                              \
    _Pragma("unroll")                                                         \
    for (int ni = 0; ni < 4; ++ni) {                                          \
      float p0 = __builtin_amdgcn_exp2f(s[ni][0]);                            \
      float p1 = __builtin_amdgcn_exp2f(s[ni][1]);                            \
      float p2 = __builtin_amdgcn_exp2f(s[ni][2]);                            \
      float p3 = __builtin_amdgcn_exp2f(s[ni][3]);                            \
      rsub += (p0 + p1) + (p2 + p3);                                          \
      const int kkh = ni >> 1, off = (ni & 1) * 4;                            \
      apk[kkh][off + 0] = (bf16_t)p0;                                         \
      apk[kkh][off + 1] = (bf16_t)p1;                                         \
      apk[kkh][off + 2] = (bf16_t)p2;                                         \
      apk[kkh][off + 3] = (bf16_t)p3;                                         \
    }                                                                         \
    lsum += rsub;                                                             \
    __builtin_amdgcn_s_setprio(1);                                            \
    _Pragma("unroll")                                                         \
    for (int kk = 0; kk < 2; ++kk) {                                          \
      _Pragma("unroll")                                                       \
      for (int ni = 0; ni < 4; ++ni) {                                        \
        const int row = ni * 16 + c;                                          \
        v8bf bv = *(const v8bf*)(Vs[CUR] + row * 64 +                         \
                                 ((kk * 32 + g * 8) ^ ((row & 7) << 3)));     \
        oacc[ni] = __builtin_amdgcn_mfma_f32_16x16x32_bf16(bv, apk[kk], oacc[ni], 0, 0, 0); \
      }                                                                       \
    }                                                                         \
    __builtin_amdgcn_s_setprio(0);                                            \
    __syncthreads();                                                          \
  }

  // NT tiles, unrolled x2 with static buffer indices
  const int NT2 = T_ / (64 * SPLIT * 2);
  for (int kt2 = 0; kt2 < NT2; ++kt2) {
    ATTN_BODY(0, 1, true)
    ATTN_BODY(1, 0, (kt2 < NT2 - 1))
  }
#undef ATTN_BODY

  // epilogue
  lsum += __shfl_xor(lsum, 16);
  lsum += __shfl_xor(lsum, 32);
  const float inv = 1.0f / lsum;
  const int q = qt * 64 + wave * 16 + c;
  if (SPLIT > 1) {
    if (g == 0) lpart[(size_t)z * (B_ * H_ * T_) + (b * H_ + h) * T_ + q] = lsum;
    bf16_t* ob = (bf16_t*)outp + ((size_t)z * M_ * D_ + ((size_t)(b * T_ + q)) * D_ + h * DH_);
    #pragma unroll
    for (int ni = 0; ni < 4; ++ni) {
      v4bf o4 = {(bf16_t)(oacc[ni][0] * inv), (bf16_t)(oacc[ni][1] * inv),
                 (bf16_t)(oacc[ni][2] * inv), (bf16_t)(oacc[ni][3] * inv)};
      *(v4bf*)(ob + ni * 16 + g * 4) = o4;
    }
  } else {
    float* ob = outp + ((size_t)(b * T_ + q)) * D_ + h * DH_;
    #pragma unroll
    for (int ni = 0; ni < 4; ++ni) {
      float4 o4 = {oacc[ni][0] * inv, oacc[ni][1] * inv, oacc[ni][2] * inv, oacc[ni][3] * inv};
      *(float4*)(ob + ni * 16 + g * 4) = o4;
    }
  }
}

extern "C" void kernel_launch(void* const* d_in, const int* in_sizes, int n_in,
                              void* d_out, int out_size, void* d_ws, size_t ws_size,
                              hipStream_t stream) {
  const float* x    = (const float*)d_in[0];
  const float* W    = (const float*)d_in[1];
  const float* bias = (const float*)d_in[2];
  float* out = (float*)d_out;
  char* ws = (char*)d_ws;
  bf16_t* xb    = (bf16_t*)(ws);                 // 4096*768*2   = 6,291,456
  bf16_t* wt    = (bf16_t*)(ws + 6291456);       // 2304*768*2   = 3,538,944
  bf16_t* qkvb  = (bf16_t*)(ws + 9830400);       // 4096*2304*2  = 18,874,368
  bf16_t* vtb   = (bf16_t*)(ws + 28704768);      // 24*64*2048*2 = 6,291,456

  k_conv   <<<dim3(3504),    dim3(256), 0, stream>>>(x, xb, W, wt);
  k_gemm   <<<dim3(18, 32),  dim3(256), 0, stream>>>(xb, wt, bias, qkvb, vtb);
  k_attn<1><<<dim3(32, 24),  dim3(256), 0, stream>>>(qkvb, vtb, out, nullptr);
}

// Round 18
// 71.497 us; speedup vs baseline: 1.1739x; 1.0239x over previous
//
#include <hip/hip_runtime.h>
#include <hip/hip_bf16.h>
#include <stdint.h>

typedef __bf16 bf16_t;
typedef __bf16 v8bf  __attribute__((ext_vector_type(8)));
typedef __bf16 v4bf  __attribute__((ext_vector_type(4)));
typedef float  f32x4 __attribute__((ext_vector_type(4)));
typedef unsigned short u16x8 __attribute__((ext_vector_type(8)));

#define B_   2
#define T_   2048
#define D_   768
#define H_   12
#define DH_  64
#define N3_  2304
#define M_   4096

// async global->LDS, 16B per lane; LDS dest must be wave-uniform base (HW adds lane*16)
__device__ __forceinline__ void gll16(const void* g, void* l) {
  __builtin_amdgcn_global_load_lds(
      (const __attribute__((address_space(1))) void*)g,
      (__attribute__((address_space(3))) void*)l,
      16, 0, 0);
}

__device__ __forceinline__ float bf2f(unsigned short u) {
  union { unsigned u; float f; } x; x.u = ((unsigned)u) << 16; return x.f;
}

// ---------------- 1+2 fused: x fp32->bf16 (blocks [0,3072)) and
//                  W [768,2304] fp32 -> Wt [2304,768] bf16 (blocks [3072,3504)) ----
__global__ __launch_bounds__(256) void k_conv(const float* __restrict__ x,
                                              bf16_t* __restrict__ xb,
                                              const float* __restrict__ W,
                                              bf16_t* __restrict__ Wt) {
  __shared__ bf16_t tile[64 * 64];
  const int tid = threadIdx.x;
  int bid = blockIdx.x;
  if (bid < 3072) {
    // conv_x: 3072*256 == M_*D_/4 exactly, no bounds check needed
    int i = bid * 256 + tid;
    float4 v = ((const float4*)x)[i];
    v4bf o = {(bf16_t)v.x, (bf16_t)v.y, (bf16_t)v.z, (bf16_t)v.w};
    *(v4bf*)(xb + (size_t)i * 4) = o;
    return;
  }
  bid -= 3072;                      // 432 blocks: 36 n-tiles x 12 k-tiles
  const int n0 = (bid % 36) * 64;   // col tile of W (row of Wt)
  const int k0 = (bid / 36) * 64;   // row tile of W
  #pragma unroll
  for (int rr = 0; rr < 4; ++rr) {
    int k  = rr * 16 + (tid >> 4);
    int gr = tid & 15;
    float4 v = *(const float4*)(W + (size_t)(k0 + k) * N3_ + n0 + gr * 4);
    v4bf o = {(bf16_t)v.x, (bf16_t)v.y, (bf16_t)v.z, (bf16_t)v.w};
    *(v4bf*)(tile + k * 64 + ((gr ^ (k & 15)) << 2)) = o;
  }
  __syncthreads();
  const int n = tid & 63, q = tid >> 6;
  bf16_t outv[16] __attribute__((aligned(16)));
  #pragma unroll
  for (int tt = 0; tt < 16; ++tt) {
    int k = q * 16 + tt;
    outv[tt] = tile[k * 64 + (((n >> 2) ^ (k & 15)) << 2) + (n & 3)];
  }
  bf16_t* dst = Wt + (size_t)(n0 + n) * D_ + k0 + q * 16;
  *(u16x8*)dst       = *(const u16x8*)outv;
  *((u16x8*)dst + 1) = *(const u16x8*)(outv + 8);
}

// ---------------- 3. GEMM: qkv = xb @ Wt^T + bias; V blocks write Vt directly ----
// R11-proven serial-staging structure (BK=32, 128x128 tile) — untouched.
// NEW (T1): 1-D grid of 576 with bijective XCD swizzle (576%8==0): each XCD gets
// 72 contiguous work-ids = 4 M-panels x all 18 N-panels (~4.3MB) -> L2-resident.
// Q columns (n < 768) pre-scaled by DH^-0.5 * log2(e); V columns (n >= 1536)
// written transposed+column-permuted to vt so attention's P stays in-register.
#define BK 32
__global__ __launch_bounds__(256) void k_gemm(const bf16_t* __restrict__ A,   // [4096,768]
                                              const bf16_t* __restrict__ Bt,  // [2304,768]
                                              const float*  __restrict__ bias,
                                              bf16_t* __restrict__ Cq,        // [4096,2304]
                                              bf16_t* __restrict__ vt) {      // [24,64,2048]
  __shared__ bf16_t As[128 * BK];
  __shared__ bf16_t Bs[128 * BK];
  const int tid  = threadIdx.x;
  const int wave = tid >> 6, lane = tid & 63;
  const int g = lane >> 4, c = lane & 15;
  const int wy = wave >> 1, wx = wave & 1;
  // XCD swizzle: orig%8 == xcd; give each xcd a contiguous 72-id slice
  const int wg  = blockIdx.x;
  const int swz = (wg & 7) * 72 + (wg >> 3);   // bijective, 576 = 8*72
  const int bm = (swz / 18) * 128, bn = (swz % 18) * 128;

  const f32x4 zf = {0.f, 0.f, 0.f, 0.f};
  f32x4 acc[4][4];
  #pragma unroll
  for (int i = 0; i < 4; ++i)
    #pragma unroll
    for (int j = 0; j < 4; ++j) acc[i][j] = zf;

  const int rA = tid >> 2;          // row within 64-row half-tile
  const int kc = (tid & 3) * 8;     // k-element within BK

  for (int k0 = 0; k0 < D_; k0 += BK) {
    __syncthreads();
    #pragma unroll
    for (int cc = 0; cc < 2; ++cc) {
      gll16(A  + (size_t)(bm + cc * 64 + rA) * D_ + k0 + kc,
            (char*)As + cc * 4096 + wave * 1024);
      gll16(Bt + (size_t)(bn + cc * 64 + rA) * D_ + k0 + kc,
            (char*)Bs + cc * 4096 + wave * 1024);
    }
    __syncthreads();
    v8bf af[4], bfr[4];
    #pragma unroll
    for (int mi = 0; mi < 4; ++mi)
      af[mi] = *(const v8bf*)(As + (wy * 64 + mi * 16 + c) * BK + g * 8);
    #pragma unroll
    for (int ni = 0; ni < 4; ++ni)
      bfr[ni] = *(const v8bf*)(Bs + (wx * 64 + ni * 16 + c) * BK + g * 8);
    #pragma unroll
    for (int mi = 0; mi < 4; ++mi)
      #pragma unroll
      for (int ni = 0; ni < 4; ++ni)
        acc[mi][ni] = __builtin_amdgcn_mfma_f32_16x16x32_bf16(af[mi], bfr[ni], acc[mi][ni], 0, 0, 0);
  }

  if (bn >= 2 * D_) {
    // V block: write transposed + column-permuted into vt (4-elem granule kept)
    const int hb = ((bn - 2 * D_) >> 6) + wx;          // head, block/wave-uniform
    #pragma unroll
    for (int ni = 0; ni < 4; ++ni) {
      float bv = bias[bn + wx * 64 + ni * 16 + c];
      const int d = ni * 16 + c;
      #pragma unroll
      for (int mi = 0; mi < 4; ++mi) {
        int row = bm + wy * 64 + mi * 16 + g * 4;      // global row, 4-aligned
        int b = row >> 11, t = row & (T_ - 1);
        int tl = t & 63;
        // s = [b5=kk | b4b3=g | b2=ih | b1b0=j] from t = [kk|ih|g|j]
        int sp = (t & ~63) | (tl & 35) | ((tl & 12) << 1) | ((tl & 16) >> 2);
        v4bf o = {(bf16_t)(acc[mi][ni][0] + bv), (bf16_t)(acc[mi][ni][1] + bv),
                  (bf16_t)(acc[mi][ni][2] + bv), (bf16_t)(acc[mi][ni][3] + bv)};
        *(v4bf*)(vt + ((size_t)((b * H_ + hb) * DH_ + d)) * T_ + sp) = o;
      }
    }
  } else {
    // Q/K block: Q columns get softmax scale folded in (768 % 128 == 0)
    const float qscale = (bn < D_) ? 0.18033688011112042f : 1.0f;  // 0.125 * log2(e)
    #pragma unroll
    for (int ni = 0; ni < 4; ++ni) {
      float bv = bias[bn + wx * 64 + ni * 16 + c];
      #pragma unroll
      for (int mi = 0; mi < 4; ++mi) {
        int row = bm + wy * 64 + mi * 16 + g * 4;
        bf16_t* d0 = Cq + (size_t)row * N3_ + bn + wx * 64 + ni * 16 + c;
        #pragma unroll
        for (int j = 0; j < 4; ++j)
          d0[(size_t)j * N3_] = (bf16_t)((acc[mi][ni][j] + bv) * qscale);
      }
    }
  }
}

// ---------------- 5. flash attention: P in-register, dbuf K/V, 1 barrier/tile ------
// R11/R15 inner structure, byte-identical (43.5us, MfmaUtil 24, 0 conflicts).
// NEW (T1): 1-D grid of 768 with bijective XCD swizzle (768%8==0): each XCD gets
// 96 contiguous work-ids = 3 complete (b,h) groups (1.5MB K/V) -> L2-resident.
template<int SPLIT>
__global__ __launch_bounds__(256) void k_attn(const bf16_t* __restrict__ qkv,
                                              const bf16_t* __restrict__ vt,
                                              float* __restrict__ outp,
                                              float* __restrict__ lpart) {
  __shared__ __align__(16) bf16_t Ks[2][64 * 64];   // K tile, rows=key, XOR-swizzled
  __shared__ __align__(16) bf16_t Vs[2][64 * 64];   // V^T tile (pre-permuted cols)
  const int tid  = threadIdx.x;
  const int wave = tid >> 6, lane = tid & 63;
  const int g = lane >> 4, c = lane & 15;
  // XCD swizzle: orig%8 == xcd; contiguous 96-id slice = 3 full bh-groups per XCD
  const int wg  = blockIdx.x;
  const int swz = (wg & 7) * 96 + (wg >> 3);   // bijective, 768 = 8*96
  const int qt = swz & 31;             // 32 q-tiles of 64 rows
  const int bh = swz >> 5;             // 24 (b,h) groups
  const int z  = (SPLIT > 1) ? blockIdx.z : 0;
  const int b = bh / H_, h = bh - b * H_;
  const int r0 = z * (T_ / SPLIT);     // key-range base

  // hoisted Q fragments: lane holds Q[q = c][d = 8g..8g+7 (+32)] (pre-scaled)
  v8bf aq[2];
  {
    const bf16_t* qb = qkv + ((size_t)(b * T_ + qt * 64 + wave * 16 + c)) * N3_ + h * DH_ + g * 8;
    aq[0] = *(const v8bf*)qb;
    aq[1] = *(const v8bf*)(qb + 32);
  }
  float lsum = 0.f;
  const f32x4 zf = {0.f, 0.f, 0.f, 0.f};
  f32x4 oacc[4];                            // O^T[d = ni*16+g*4+j][q = c]
  #pragma unroll
  for (int ni = 0; ni < 4; ++ni) oacc[ni] = zf;

  // staging pointers (pre-swizzled global source, linear LDS dest — rule #21)
  const int rS  = tid >> 3;   // 0..31
  const int grS = tid & 7;
  const bf16_t* gK[2];
  const bf16_t* gV[2];
  #pragma unroll
  for (int cc = 0; cc < 2; ++cc) {
    int r    = cc * 32 + rS;
    int colk = ((grS ^ (r & 7)) << 3);
    gK[cc] = qkv + ((size_t)(b * T_ + r0 + r)) * N3_ + D_ + h * DH_ + colk;
    gV[cc] = vt + ((size_t)(bh * DH_ + r)) * T_ + r0 + colk;
  }

  // prologue: stage tile 0 into buf 0
  #pragma unroll
  for (int cc = 0; cc < 2; ++cc) {
    gll16(gK[cc], (char*)Ks[0] + cc * 4096 + wave * 1024);
    gll16(gV[cc], (char*)Vs[0] + cc * 4096 + wave * 1024);
    gK[cc] += 64 * (size_t)N3_;
    gV[cc] += 64;
  }
  __syncthreads();

#define ATTN_BODY(CUR, NXT, DOSTAGE)                                          \
  {                                                                           \
    if (DOSTAGE) {                                                            \
      _Pragma("unroll")                                                       \
      for (int cc = 0; cc < 2; ++cc) {                                        \
        gll16(gK[cc], (char*)Ks[NXT] + cc * 4096 + wave * 1024);              \
        gll16(gV[cc], (char*)Vs[NXT] + cc * 4096 + wave * 1024);              \
        gK[cc] += 64 * (size_t)N3_;                                           \
        gV[cc] += 64;                                                         \
      }                                                                       \
    }                                                                         \
    f32x4 s[4] = {zf, zf, zf, zf};                                            \
    __builtin_amdgcn_s_setprio(1);                                            \
    _Pragma("unroll")                                                         \
    for (int kk = 0; kk < 2; ++kk) {                                          \
      _Pragma("unroll")                                                       \
      for (int ni = 0; ni < 4; ++ni) {                                        \
        const int row = ni * 16 + c;                                          \
        v8bf bk = *(const v8bf*)(Ks[CUR] + row * 64 +                         \
                                 ((kk * 32 + g * 8) ^ ((row & 7) << 3)));     \
        s[ni] = __builtin_amdgcn_mfma_f32_16x16x32_bf16(bk, aq[kk], s[ni], 0, 0, 0); \
      }                                                                       \
    }                                                                         \
    __builtin_amdgcn_s_setprio(0);                                            \
    float rsub = 0.f;                                                         \
    v8bf apk[2];                                                              \
    _Pragma("unroll")                                                         \
    for (int ni = 0; ni < 4; ++ni) {                                          \
      float p0 = __builtin_amdgcn_exp2f(s[ni][0]);                            \
      float p1 = __builtin_amdgcn_exp2f(s[ni][1]);                            \
      float p2 = __builtin_amdgcn_exp2f(s[ni][2]);                            \
      float p3 = __builtin_amdgcn_exp2f(s[ni][3]);                            \
      rsub += (p0 + p1) + (p2 + p3);                                          \
      const int kkh = ni >> 1, off = (ni & 1) * 4;                            \
      apk[kkh][off + 0] = (bf16_t)p0;                                         \
      apk[kkh][off + 1] = (bf16_t)p1;                                         \
      apk[kkh][off + 2] = (bf16_t)p2;                                         \
      apk[kkh][off + 3] = (bf16_t)p3;                                         \
    }                                                                         \
    lsum += rsub;                                                             \
    __builtin_amdgcn_s_setprio(1);                                            \
    _Pragma("unroll")                                                         \
    for (int kk = 0; kk < 2; ++kk) {                                          \
      _Pragma("unroll")                                                       \
      for (int ni = 0; ni < 4; ++ni) {                                        \
        const int row = ni * 16 + c;                                          \
        v8bf bv = *(const v8bf*)(Vs[CUR] + row * 64 +                         \
                                 ((kk * 32 + g * 8) ^ ((row & 7) << 3)));     \
        oacc[ni] = __builtin_amdgcn_mfma_f32_16x16x32_bf16(bv, apk[kk], oacc[ni], 0, 0, 0); \
      }                                                                       \
    }                                                                         \
    __builtin_amdgcn_s_setprio(0);                                            \
    __syncthreads();                                                          \
  }

  // NT tiles, unrolled x2 with static buffer indices
  const int NT2 = T_ / (64 * SPLIT * 2);
  for (int kt2 = 0; kt2 < NT2; ++kt2) {
    ATTN_BODY(0, 1, true)
    ATTN_BODY(1, 0, (kt2 < NT2 - 1))
  }
#undef ATTN_BODY

  // epilogue
  lsum += __shfl_xor(lsum, 16);
  lsum += __shfl_xor(lsum, 32);
  const float inv = 1.0f / lsum;
  const int q = qt * 64 + wave * 16 + c;
  if (SPLIT > 1) {
    if (g == 0) lpart[(size_t)z * (B_ * H_ * T_) + (b * H_ + h) * T_ + q] = lsum;
    bf16_t* ob = (bf16_t*)outp + ((size_t)z * M_ * D_ + ((size_t)(b * T_ + q)) * D_ + h * DH_);
    #pragma unroll
    for (int ni = 0; ni < 4; ++ni) {
      v4bf o4 = {(bf16_t)(oacc[ni][0] * inv), (bf16_t)(oacc[ni][1] * inv),
                 (bf16_t)(oacc[ni][2] * inv), (bf16_t)(oacc[ni][3] * inv)};
      *(v4bf*)(ob + ni * 16 + g * 4) = o4;
    }
  } else {
    float* ob = outp + ((size_t)(b * T_ + q)) * D_ + h * DH_;
    #pragma unroll
    for (int ni = 0; ni < 4; ++ni) {
      float4 o4 = {oacc[ni][0] * inv, oacc[ni][1] * inv, oacc[ni][2] * inv, oacc[ni][3] * inv};
      *(float4*)(ob + ni * 16 + g * 4) = o4;
    }
  }
}

extern "C" void kernel_launch(void* const* d_in, const int* in_sizes, int n_in,
                              void* d_out, int out_size, void* d_ws, size_t ws_size,
                              hipStream_t stream) {
  const float* x    = (const float*)d_in[0];
  const float* W    = (const float*)d_in[1];
  const float* bias = (const float*)d_in[2];
  float* out = (float*)d_out;
  char* ws = (char*)d_ws;
  bf16_t* xb    = (bf16_t*)(ws);                 // 4096*768*2   = 6,291,456
  bf16_t* wt    = (bf16_t*)(ws + 6291456);       // 2304*768*2   = 3,538,944
  bf16_t* qkvb  = (bf16_t*)(ws + 9830400);       // 4096*2304*2  = 18,874,368
  bf16_t* vtb   = (bf16_t*)(ws + 28704768);      // 24*64*2048*2 = 6,291,456

  k_conv   <<<dim3(3504),    dim3(256), 0, stream>>>(x, xb, W, wt);
  k_gemm   <<<dim3(576),     dim3(256), 0, stream>>>(xb, wt, bias, qkvb, vtb);
  k_attn<1><<<dim3(768),     dim3(256), 0, stream>>>(qkvb, vtb, out, nullptr);
}

// Round 19
// 71.312 us; speedup vs baseline: 1.1770x; 1.0026x over previous
//
#include <hip/hip_runtime.h>
#include <hip/hip_bf16.h>
#include <stdint.h>

typedef __bf16 bf16_t;
typedef __bf16 v8bf  __attribute__((ext_vector_type(8)));
typedef __bf16 v4bf  __attribute__((ext_vector_type(4)));
typedef float  f32x4 __attribute__((ext_vector_type(4)));
typedef unsigned short u16x8 __attribute__((ext_vector_type(8)));

#define B_   2
#define T_   2048
#define D_   768
#define H_   12
#define DH_  64
#define N3_  2304
#define M_   4096

// async global->LDS, 16B per lane; LDS dest must be wave-uniform base (HW adds lane*16)
__device__ __forceinline__ void gll16(const void* g, void* l) {
  __builtin_amdgcn_global_load_lds(
      (const __attribute__((address_space(1))) void*)g,
      (__attribute__((address_space(3))) void*)l,
      16, 0, 0);
}

__device__ __forceinline__ float bf2f(unsigned short u) {
  union { unsigned u; float f; } x; x.u = ((unsigned)u) << 16; return x.f;
}

// ---------------- 1+2 fused: x fp32->bf16 (blocks [0,3072)) and
//                  W [768,2304] fp32 -> Wt [2304,768] bf16 (blocks [3072,3504)) ----
__global__ __launch_bounds__(256) void k_conv(const float* __restrict__ x,
                                              bf16_t* __restrict__ xb,
                                              const float* __restrict__ W,
                                              bf16_t* __restrict__ Wt) {
  __shared__ bf16_t tile[64 * 64];
  const int tid = threadIdx.x;
  int bid = blockIdx.x;
  if (bid < 3072) {
    // conv_x: 3072*256 == M_*D_/4 exactly, no bounds check needed
    int i = bid * 256 + tid;
    float4 v = ((const float4*)x)[i];
    v4bf o = {(bf16_t)v.x, (bf16_t)v.y, (bf16_t)v.z, (bf16_t)v.w};
    *(v4bf*)(xb + (size_t)i * 4) = o;
    return;
  }
  bid -= 3072;                      // 432 blocks: 36 n-tiles x 12 k-tiles
  const int n0 = (bid % 36) * 64;   // col tile of W (row of Wt)
  const int k0 = (bid / 36) * 64;   // row tile of W
  #pragma unroll
  for (int rr = 0; rr < 4; ++rr) {
    int k  = rr * 16 + (tid >> 4);
    int gr = tid & 15;
    float4 v = *(const float4*)(W + (size_t)(k0 + k) * N3_ + n0 + gr * 4);
    v4bf o = {(bf16_t)v.x, (bf16_t)v.y, (bf16_t)v.z, (bf16_t)v.w};
    *(v4bf*)(tile + k * 64 + ((gr ^ (k & 15)) << 2)) = o;
  }
  __syncthreads();
  const int n = tid & 63, q = tid >> 6;
  bf16_t outv[16] __attribute__((aligned(16)));
  #pragma unroll
  for (int tt = 0; tt < 16; ++tt) {
    int k = q * 16 + tt;
    outv[tt] = tile[k * 64 + (((n >> 2) ^ (k & 15)) << 2) + (n & 3)];
  }
  bf16_t* dst = Wt + (size_t)(n0 + n) * D_ + k0 + q * 16;
  *(u16x8*)dst       = *(const u16x8*)outv;
  *((u16x8*)dst + 1) = *(const u16x8*)(outv + 8);
}

// ---------------- 3. GEMM: qkv = xb @ Wt^T + bias; V blocks write Vt directly ----
// R11-proven serial-staging structure (BK=32, 128x128 tile) — untouched.
// NEW (T1): 1-D grid of 576 with bijective XCD swizzle (576%8==0): each XCD gets
// 72 contiguous work-ids = 4 M-panels x all 18 N-panels (~4.3MB) -> L2-resident.
// Q columns (n < 768) pre-scaled by DH^-0.5 * log2(e); V columns (n >= 1536)
// written transposed+column-permuted to vt so attention's P stays in-register.
#define BK 32
__global__ __launch_bounds__(256) void k_gemm(const bf16_t* __restrict__ A,   // [4096,768]
                                              const bf16_t* __restrict__ Bt,  // [2304,768]
                                              const float*  __restrict__ bias,
                                              bf16_t* __restrict__ Cq,        // [4096,2304]
                                              bf16_t* __restrict__ vt) {      // [24,64,2048]
  __shared__ bf16_t As[128 * BK];
  __shared__ bf16_t Bs[128 * BK];
  const int tid  = threadIdx.x;
  const int wave = tid >> 6, lane = tid & 63;
  const int g = lane >> 4, c = lane & 15;
  const int wy = wave >> 1, wx = wave & 1;
  // XCD swizzle: orig%8 == xcd; give each xcd a contiguous 72-id slice
  const int wg  = blockIdx.x;
  const int swz = (wg & 7) * 72 + (wg >> 3);   // bijective, 576 = 8*72
  const int bm = (swz / 18) * 128, bn = (swz % 18) * 128;

  const f32x4 zf = {0.f, 0.f, 0.f, 0.f};
  f32x4 acc[4][4];
  #pragma unroll
  for (int i = 0; i < 4; ++i)
    #pragma unroll
    for (int j = 0; j < 4; ++j) acc[i][j] = zf;

  const int rA = tid >> 2;          // row within 64-row half-tile
  const int kc = (tid & 3) * 8;     // k-element within BK

  for (int k0 = 0; k0 < D_; k0 += BK) {
    __syncthreads();
    #pragma unroll
    for (int cc = 0; cc < 2; ++cc) {
      gll16(A  + (size_t)(bm + cc * 64 + rA) * D_ + k0 + kc,
            (char*)As + cc * 4096 + wave * 1024);
      gll16(Bt + (size_t)(bn + cc * 64 + rA) * D_ + k0 + kc,
            (char*)Bs + cc * 4096 + wave * 1024);
    }
    __syncthreads();
    v8bf af[4], bfr[4];
    #pragma unroll
    for (int mi = 0; mi < 4; ++mi)
      af[mi] = *(const v8bf*)(As + (wy * 64 + mi * 16 + c) * BK + g * 8);
    #pragma unroll
    for (int ni = 0; ni < 4; ++ni)
      bfr[ni] = *(const v8bf*)(Bs + (wx * 64 + ni * 16 + c) * BK + g * 8);
    #pragma unroll
    for (int mi = 0; mi < 4; ++mi)
      #pragma unroll
      for (int ni = 0; ni < 4; ++ni)
        acc[mi][ni] = __builtin_amdgcn_mfma_f32_16x16x32_bf16(af[mi], bfr[ni], acc[mi][ni], 0, 0, 0);
  }

  if (bn >= 2 * D_) {
    // V block: write transposed + column-permuted into vt (4-elem granule kept)
    const int hb = ((bn - 2 * D_) >> 6) + wx;          // head, block/wave-uniform
    #pragma unroll
    for (int ni = 0; ni < 4; ++ni) {
      float bv = bias[bn + wx * 64 + ni * 16 + c];
      const int d = ni * 16 + c;
      #pragma unroll
      for (int mi = 0; mi < 4; ++mi) {
        int row = bm + wy * 64 + mi * 16 + g * 4;      // global row, 4-aligned
        int b = row >> 11, t = row & (T_ - 1);
        int tl = t & 63;
        // s = [b5=kk | b4b3=g | b2=ih | b1b0=j] from t = [kk|ih|g|j]
        int sp = (t & ~63) | (tl & 35) | ((tl & 12) << 1) | ((tl & 16) >> 2);
        v4bf o = {(bf16_t)(acc[mi][ni][0] + bv), (bf16_t)(acc[mi][ni][1] + bv),
                  (bf16_t)(acc[mi][ni][2] + bv), (bf16_t)(acc[mi][ni][3] + bv)};
        *(v4bf*)(vt + ((size_t)((b * H_ + hb) * DH_ + d)) * T_ + sp) = o;
      }
    }
  } else {
    // Q/K block: Q columns get softmax scale folded in (768 % 128 == 0)
    const float qscale = (bn < D_) ? 0.18033688011112042f : 1.0f;  // 0.125 * log2(e)
    #pragma unroll
    for (int ni = 0; ni < 4; ++ni) {
      float bv = bias[bn + wx * 64 + ni * 16 + c];
      #pragma unroll
      for (int mi = 0; mi < 4; ++mi) {
        int row = bm + wy * 64 + mi * 16 + g * 4;
        bf16_t* d0 = Cq + (size_t)row * N3_ + bn + wx * 64 + ni * 16 + c;
        #pragma unroll
        for (int j = 0; j < 4; ++j)
          d0[(size_t)j * N3_] = (bf16_t)((acc[mi][ni][j] + bv) * qscale);
      }
    }
  }
}

// ---------------- 5. flash attention: P in-register, dbuf K/V, 1 barrier/tile ------
// R11/R15 inner structure, byte-identical (43.5us, MfmaUtil 24, 0 conflicts).
// NEW (T1): 1-D grid of 768 with bijective XCD swizzle (768%8==0): each XCD gets
// 96 contiguous work-ids = 3 complete (b,h) groups (1.5MB K/V) -> L2-resident.
template<int SPLIT>
__global__ __launch_bounds__(256) void k_attn(const bf16_t* __restrict__ qkv,
                                              const bf16_t* __restrict__ vt,
                                              float* __restrict__ outp,
                                              float* __restrict__ lpart) {
  __shared__ __align__(16) bf16_t Ks[2][64 * 64];   // K tile, rows=key, XOR-swizzled
  __shared__ __align__(16) bf16_t Vs[2][64 * 64];   // V^T tile (pre-permuted cols)
  const int tid  = threadIdx.x;
  const int wave = tid >> 6, lane = tid & 63;
  const int g = lane >> 4, c = lane & 15;
  // XCD swizzle: orig%8 == xcd; contiguous 96-id slice = 3 full bh-groups per XCD
  const int wg  = blockIdx.x;
  const int swz = (wg & 7) * 96 + (wg >> 3);   // bijective, 768 = 8*96
  const int qt = swz & 31;             // 32 q-tiles of 64 rows
  const int bh = swz >> 5;             // 24 (b,h) groups
  const int z  = (SPLIT > 1) ? blockIdx.z : 0;
  const int b = bh / H_, h = bh - b * H_;
  const int r0 = z * (T_ / SPLIT);     // key-range base

  // hoisted Q fragments: lane holds Q[q = c][d = 8g..8g+7 (+32)] (pre-scaled)
  v8bf aq[2];
  {
    const bf16_t* qb = qkv + ((size_t)(b * T_ + qt * 64 + wave * 16 + c)) * N3_ + h * DH_ + g * 8;
    aq[0] = *(const v8bf*)qb;
    aq[1] = *(const v8bf*)(qb + 32);
  }
  float lsum = 0.f;
  const f32x4 zf = {0.f, 0.f, 0.f, 0.f};
  f32x4 oacc[4];                            // O^T[d = ni*16+g*4+j][q = c]
  #pragma unroll
  for (int ni = 0; ni < 4; ++ni) oacc[ni] = zf;

  // staging pointers (pre-swizzled global source, linear LDS dest — rule #21)
  const int rS  = tid >> 3;   // 0..31
  const int grS = tid & 7;
  const bf16_t* gK[2];
  const bf16_t* gV[2];
  #pragma unroll
  for (int cc = 0; cc < 2; ++cc) {
    int r    = cc * 32 + rS;
    int colk = ((grS ^ (r & 7)) << 3);
    gK[cc] = qkv + ((size_t)(b * T_ + r0 + r)) * N3_ + D_ + h * DH_ + colk;
    gV[cc] = vt + ((size_t)(bh * DH_ + r)) * T_ + r0 + colk;
  }

  // prologue: stage tile 0 into buf 0
  #pragma unroll
  for (int cc = 0; cc < 2; ++cc) {
    gll16(gK[cc], (char*)Ks[0] + cc * 4096 + wave * 1024);
    gll16(gV[cc], (char*)Vs[0] + cc * 4096 + wave * 1024);
    gK[cc] += 64 * (size_t)N3_;
    gV[cc] += 64;
  }
  __syncthreads();

#define ATTN_BODY(CUR, NXT, DOSTAGE)                                          \
  {                                                                           \
    if (DOSTAGE) {                                                            \
      _Pragma("unroll")                                                       \
      for (int cc = 0; cc < 2; ++cc) {                                        \
        gll16(gK[cc], (char*)Ks[NXT] + cc * 4096 + wave * 1024);              \
        gll16(gV[cc], (char*)Vs[NXT] + cc * 4096 + wave * 1024);              \
        gK[cc] += 64 * (size_t)N3_;                                           \
        gV[cc] += 64;                                                         \
      }                                                                       \
    }                                                                         \
    f32x4 s[4] = {zf, zf, zf, zf};                                            \
    __builtin_amdgcn_s_setprio(1);                                            \
    _Pragma("unroll")                                                         \
    for (int kk = 0; kk < 2; ++kk) {                                          \
      _Pragma("unroll")                                                       \
      for (int ni = 0; ni < 4; ++ni) {                                        \
        const int row = ni * 16 + c;                                          \
        v8bf bk = *(const v8bf*)(Ks[CUR] + row * 64 +                         \
                                 ((kk * 32 + g * 8) ^ ((row & 7) << 3)));     \
        s[ni] = __builtin_amdgcn_mfma_f32_16x16x32_bf16(bk, aq[kk], s[ni], 0, 0, 0); \
      }                                                                       \
    }                                                                         \
    __builtin_amdgcn_s_setprio(0);                                            \
    float rsub = 0.f;                                                         \
    v8bf apk[2];                                                              \
    _Pragma("unroll")                                                         \
    for (int ni = 0; ni < 4; ++ni) {                                          \
      float p0 = __builtin_amdgcn_exp2f(s[ni][0]);                            \
      float p1 = __builtin_amdgcn_exp2f(s[ni][1]);                            \
      float p2 = __builtin_amdgcn_exp2f(s[ni][2]);                            \
      float p3 = __builtin_amdgcn_exp2f(s[ni][3]);                            \
      rsub += (p0 + p1) + (p2 + p3);                                          \
      const int kkh = ni >> 1, off = (ni & 1) * 4;                            \
      apk[kkh][off + 0] = (bf16_t)p0;                                         \
      apk[kkh][off + 1] = (bf16_t)p1;                                         \
      apk[kkh][off + 2] = (bf16_t)p2;                                         \
      apk[kkh][off + 3] = (bf16_t)p3;                                         \
    }                                                                         \
    lsum += rsub;                                                             \
    __builtin_amdgcn_s_setprio(1);                                            \
    _Pragma("unroll")                                                         \
    for (int kk = 0; kk < 2; ++kk) {                                          \
      _Pragma("unroll")                                                       \
      for (int ni = 0; ni < 4; ++ni) {                                        \
        const int row = ni * 16 + c;                                          \
        v8bf bv = *(const v8bf*)(Vs[CUR] + row * 64 +                         \
                                 ((kk * 32 + g * 8) ^ ((row & 7) << 3)));     \
        oacc[ni] = __builtin_amdgcn_mfma_f32_16x16x32_bf16(bv, apk[kk], oacc[ni], 0, 0, 0); \
      }                                                                       \
    }                                                                         \
    __builtin_amdgcn_s_setprio(0);                                            \
    __syncthreads();                                                          \
  }

  // NT tiles, unrolled x2 with static buffer indices
  const int NT2 = T_ / (64 * SPLIT * 2);
  for (int kt2 = 0; kt2 < NT2; ++kt2) {
    ATTN_BODY(0, 1, true)
    ATTN_BODY(1, 0, (kt2 < NT2 - 1))
  }
#undef ATTN_BODY

  // epilogue
  lsum += __shfl_xor(lsum, 16);
  lsum += __shfl_xor(lsum, 32);
  const float inv = 1.0f / lsum;
  const int q = qt * 64 + wave * 16 + c;
  if (SPLIT > 1) {
    if (g == 0) lpart[(size_t)z * (B_ * H_ * T_) + (b * H_ + h) * T_ + q] = lsum;
    bf16_t* ob = (bf16_t*)outp + ((size_t)z * M_ * D_ + ((size_t)(b * T_ + q)) * D_ + h * DH_);
    #pragma unroll
    for (int ni = 0; ni < 4; ++ni) {
      v4bf o4 = {(bf16_t)(oacc[ni][0] * inv), (bf16_t)(oacc[ni][1] * inv),
                 (bf16_t)(oacc[ni][2] * inv), (bf16_t)(oacc[ni][3] * inv)};
      *(v4bf*)(ob + ni * 16 + g * 4) = o4;
    }
  } else {
    float* ob = outp + ((size_t)(b * T_ + q)) * D_ + h * DH_;
    #pragma unroll
    for (int ni = 0; ni < 4; ++ni) {
      float4 o4 = {oacc[ni][0] * inv, oacc[ni][1] * inv, oacc[ni][2] * inv, oacc[ni][3] * inv};
      *(float4*)(ob + ni * 16 + g * 4) = o4;
    }
  }
}

extern "C" void kernel_launch(void* const* d_in, const int* in_sizes, int n_in,
                              void* d_out, int out_size, void* d_ws, size_t ws_size,
                              hipStream_t stream) {
  const float* x    = (const float*)d_in[0];
  const float* W    = (const float*)d_in[1];
  const float* bias = (const float*)d_in[2];
  float* out = (float*)d_out;
  char* ws = (char*)d_ws;
  bf16_t* xb    = (bf16_t*)(ws);                 // 4096*768*2   = 6,291,456
  bf16_t* wt    = (bf16_t*)(ws + 6291456);       // 2304*768*2   = 3,538,944
  bf16_t* qkvb  = (bf16_t*)(ws + 9830400);       // 4096*2304*2  = 18,874,368
  bf16_t* vtb   = (bf16_t*)(ws + 28704768);      // 24*64*2048*2 = 6,291,456

  k_conv   <<<dim3(3504),    dim3(256), 0, stream>>>(x, xb, W, wt);
  k_gemm   <<<dim3(576),     dim3(256), 0, stream>>>(xb, wt, bias, qkvb, vtb);
  k_attn<1><<<dim3(768),     dim3(256), 0, stream>>>(qkvb, vtb, out, nullptr);
}

// Round 20
// 70.886 us; speedup vs baseline: 1.1841x; 1.0060x over previous
//
#include <hip/hip_runtime.h>
#include <hip/hip_bf16.h>
#include <stdint.h>

typedef __bf16 bf16_t;
typedef __bf16 v8bf  __attribute__((ext_vector_type(8)));
typedef __bf16 v4bf  __attribute__((ext_vector_type(4)));
typedef float  f32x4 __attribute__((ext_vector_type(4)));
typedef unsigned short u16x8 __attribute__((ext_vector_type(8)));

#define B_   2
#define T_   2048
#define D_   768
#define H_   12
#define DH_  64
#define N3_  2304
#define M_   4096

// async global->LDS, 16B per lane; LDS dest must be wave-uniform base (HW adds lane*16)
__device__ __forceinline__ void gll16(const void* g, void* l) {
  __builtin_amdgcn_global_load_lds(
      (const __attribute__((address_space(1))) void*)g,
      (__attribute__((address_space(3))) void*)l,
      16, 0, 0);
}

__device__ __forceinline__ float bf2f(unsigned short u) {
  union { unsigned u; float f; } x; x.u = ((unsigned)u) << 16; return x.f;
}

// ---------------- 1+2 fused: x fp32->bf16 (blocks [0,3072)) and
//                  W [768,2304] fp32 -> Wt [2304,768] bf16 (blocks [3072,3504)) ----
__global__ __launch_bounds__(256) void k_conv(const float* __restrict__ x,
                                              bf16_t* __restrict__ xb,
                                              const float* __restrict__ W,
                                              bf16_t* __restrict__ Wt) {
  __shared__ bf16_t tile[64 * 64];
  const int tid = threadIdx.x;
  int bid = blockIdx.x;
  if (bid < 3072) {
    // conv_x: 3072*256 == M_*D_/4 exactly, no bounds check needed
    int i = bid * 256 + tid;
    float4 v = ((const float4*)x)[i];
    v4bf o = {(bf16_t)v.x, (bf16_t)v.y, (bf16_t)v.z, (bf16_t)v.w};
    *(v4bf*)(xb + (size_t)i * 4) = o;
    return;
  }
  bid -= 3072;                      // 432 blocks: 36 n-tiles x 12 k-tiles
  const int n0 = (bid % 36) * 64;   // col tile of W (row of Wt)
  const int k0 = (bid / 36) * 64;   // row tile of W
  #pragma unroll
  for (int rr = 0; rr < 4; ++rr) {
    int k  = rr * 16 + (tid >> 4);
    int gr = tid & 15;
    float4 v = *(const float4*)(W + (size_t)(k0 + k) * N3_ + n0 + gr * 4);
    v4bf o = {(bf16_t)v.x, (bf16_t)v.y, (bf16_t)v.z, (bf16_t)v.w};
    *(v4bf*)(tile + k * 64 + ((gr ^ (k & 15)) << 2)) = o;
  }
  __syncthreads();
  const int n = tid & 63, q = tid >> 6;
  bf16_t outv[16] __attribute__((aligned(16)));
  #pragma unroll
  for (int tt = 0; tt < 16; ++tt) {
    int k = q * 16 + tt;
    outv[tt] = tile[k * 64 + (((n >> 2) ^ (k & 15)) << 2) + (n & 3)];
  }
  bf16_t* dst = Wt + (size_t)(n0 + n) * D_ + k0 + q * 16;
  *(u16x8*)dst       = *(const u16x8*)outv;
  *((u16x8*)dst + 1) = *(const u16x8*)(outv + 8);
}

// ---------------- 3. GEMM: qkv = xb @ Wt^T + bias; V blocks write Vt directly ----
// R11-proven serial-staging structure (BK=32, 128x128 tile) — untouched.
// T1 v2: rectangular XCD chunking. Each XCD gets an 8M x 9N panel rectangle:
// A-slice 1.57MB + B-slice 1.77MB = 3.3MB < 4MB L2 (v1's 4M x 18N = 4.3MB
// slightly overflowed). Bijective: 576 = 8 xcd * 72, rect = (xcd>>1, xcd&1).
// Q columns (n < 768) pre-scaled by DH^-0.5 * log2(e); V columns (n >= 1536)
// written transposed+column-permuted to vt so attention's P stays in-register.
#define BK 32
__global__ __launch_bounds__(256) void k_gemm(const bf16_t* __restrict__ A,   // [4096,768]
                                              const bf16_t* __restrict__ Bt,  // [2304,768]
                                              const float*  __restrict__ bias,
                                              bf16_t* __restrict__ Cq,        // [4096,2304]
                                              bf16_t* __restrict__ vt) {      // [24,64,2048]
  __shared__ bf16_t As[128 * BK];
  __shared__ bf16_t Bs[128 * BK];
  const int tid  = threadIdx.x;
  const int wave = tid >> 6, lane = tid & 63;
  const int g = lane >> 4, c = lane & 15;
  const int wy = wave >> 1, wx = wave & 1;
  // XCD rectangle chunking: xcd = wg&7 -> rect (mchunk 8 panels, nchunk 9 panels)
  const int wg  = blockIdx.x;
  const int xcd = wg & 7, id = wg >> 3;        // id in [0,72)
  const int bm = ((xcd >> 1) * 8 + id / 9) * 128;
  const int bn = ((xcd & 1) * 9 + id % 9) * 128;

  const f32x4 zf = {0.f, 0.f, 0.f, 0.f};
  f32x4 acc[4][4];
  #pragma unroll
  for (int i = 0; i < 4; ++i)
    #pragma unroll
    for (int j = 0; j < 4; ++j) acc[i][j] = zf;

  const int rA = tid >> 2;          // row within 64-row half-tile
  const int kc = (tid & 3) * 8;     // k-element within BK

  for (int k0 = 0; k0 < D_; k0 += BK) {
    __syncthreads();
    #pragma unroll
    for (int cc = 0; cc < 2; ++cc) {
      gll16(A  + (size_t)(bm + cc * 64 + rA) * D_ + k0 + kc,
            (char*)As + cc * 4096 + wave * 1024);
      gll16(Bt + (size_t)(bn + cc * 64 + rA) * D_ + k0 + kc,
            (char*)Bs + cc * 4096 + wave * 1024);
    }
    __syncthreads();
    v8bf af[4], bfr[4];
    #pragma unroll
    for (int mi = 0; mi < 4; ++mi)
      af[mi] = *(const v8bf*)(As + (wy * 64 + mi * 16 + c) * BK + g * 8);
    #pragma unroll
    for (int ni = 0; ni < 4; ++ni)
      bfr[ni] = *(const v8bf*)(Bs + (wx * 64 + ni * 16 + c) * BK + g * 8);
    #pragma unroll
    for (int mi = 0; mi < 4; ++mi)
      #pragma unroll
      for (int ni = 0; ni < 4; ++ni)
        acc[mi][ni] = __builtin_amdgcn_mfma_f32_16x16x32_bf16(af[mi], bfr[ni], acc[mi][ni], 0, 0, 0);
  }

  if (bn >= 2 * D_) {
    // V block: write transposed + column-permuted into vt (4-elem granule kept)
    const int hb = ((bn - 2 * D_) >> 6) + wx;          // head, block/wave-uniform
    #pragma unroll
    for (int ni = 0; ni < 4; ++ni) {
      float bv = bias[bn + wx * 64 + ni * 16 + c];
      const int d = ni * 16 + c;
      #pragma unroll
      for (int mi = 0; mi < 4; ++mi) {
        int row = bm + wy * 64 + mi * 16 + g * 4;      // global row, 4-aligned
        int b = row >> 11, t = row & (T_ - 1);
        int tl = t & 63;
        // s = [b5=kk | b4b3=g | b2=ih | b1b0=j] from t = [kk|ih|g|j]
        int sp = (t & ~63) | (tl & 35) | ((tl & 12) << 1) | ((tl & 16) >> 2);
        v4bf o = {(bf16_t)(acc[mi][ni][0] + bv), (bf16_t)(acc[mi][ni][1] + bv),
                  (bf16_t)(acc[mi][ni][2] + bv), (bf16_t)(acc[mi][ni][3] + bv)};
        *(v4bf*)(vt + ((size_t)((b * H_ + hb) * DH_ + d)) * T_ + sp) = o;
      }
    }
  } else {
    // Q/K block: Q columns get softmax scale folded in (768 % 128 == 0)
    const float qscale = (bn < D_) ? 0.18033688011112042f : 1.0f;  // 0.125 * log2(e)
    #pragma unroll
    for (int ni = 0; ni < 4; ++ni) {
      float bv = bias[bn + wx * 64 + ni * 16 + c];
      #pragma unroll
      for (int mi = 0; mi < 4; ++mi) {
        int row = bm + wy * 64 + mi * 16 + g * 4;
        bf16_t* d0 = Cq + (size_t)row * N3_ + bn + wx * 64 + ni * 16 + c;
        #pragma unroll
        for (int j = 0; j < 4; ++j)
          d0[(size_t)j * N3_] = (bf16_t)((acc[mi][ni][j] + bv) * qscale);
      }
    }
  }
}

// ---------------- 5. flash attention: P in-register, dbuf K/V, 1 barrier/tile ------
// R11/R15 inner structure + R19 XCD swizzle (FETCH 52->9.3MB confirmed). Unchanged.
template<int SPLIT>
__global__ __launch_bounds__(256) void k_attn(const bf16_t* __restrict__ qkv,
                                              const bf16_t* __restrict__ vt,
                                              float* __restrict__ outp,
                                              float* __restrict__ lpart) {
  __shared__ __align__(16) bf16_t Ks[2][64 * 64];   // K tile, rows=key, XOR-swizzled
  __shared__ __align__(16) bf16_t Vs[2][64 * 64];   // V^T tile (pre-permuted cols)
  const int tid  = threadIdx.x;
  const int wave = tid >> 6, lane = tid & 63;
  const int g = lane >> 4, c = lane & 15;
  // XCD swizzle: orig%8 == xcd; contiguous 96-id slice = 3 full bh-groups per XCD
  const int wg  = blockIdx.x;
  const int swz = (wg & 7) * 96 + (wg >> 3);   // bijective, 768 = 8*96
  const int qt = swz & 31;             // 32 q-tiles of 64 rows
  const int bh = swz >> 5;             // 24 (b,h) groups
  const int z  = (SPLIT > 1) ? blockIdx.z : 0;
  const int b = bh / H_, h = bh - b * H_;
  const int r0 = z * (T_ / SPLIT);     // key-range base

  // hoisted Q fragments: lane holds Q[q = c][d = 8g..8g+7 (+32)] (pre-scaled)
  v8bf aq[2];
  {
    const bf16_t* qb = qkv + ((size_t)(b * T_ + qt * 64 + wave * 16 + c)) * N3_ + h * DH_ + g * 8;
    aq[0] = *(const v8bf*)qb;
    aq[1] = *(const v8bf*)(qb + 32);
  }
  float lsum = 0.f;
  const f32x4 zf = {0.f, 0.f, 0.f, 0.f};
  f32x4 oacc[4];                            // O^T[d = ni*16+g*4+j][q = c]
  #pragma unroll
  for (int ni = 0; ni < 4; ++ni) oacc[ni] = zf;

  // staging pointers (pre-swizzled global source, linear LDS dest — rule #21)
  const int rS  = tid >> 3;   // 0..31
  const int grS = tid & 7;
  const bf16_t* gK[2];
  const bf16_t* gV[2];
  #pragma unroll
  for (int cc = 0; cc < 2; ++cc) {
    int r    = cc * 32 + rS;
    int colk = ((grS ^ (r & 7)) << 3);
    gK[cc] = qkv + ((size_t)(b * T_ + r0 + r)) * N3_ + D_ + h * DH_ + colk;
    gV[cc] = vt + ((size_t)(bh * DH_ + r)) * T_ + r0 + colk;
  }

  // prologue: stage tile 0 into buf 0
  #pragma unroll
  for (int cc = 0; cc < 2; ++cc) {
    gll16(gK[cc], (char*)Ks[0] + cc * 4096 + wave * 1024);
    gll16(gV[cc], (char*)Vs[0] + cc * 4096 + wave * 1024);
    gK[cc] += 64 * (size_t)N3_;
    gV[cc] += 64;
  }
  __syncthreads();

#define ATTN_BODY(CUR, NXT, DOSTAGE)                                          \
  {                                                                           \
    if (DOSTAGE) {                                                            \
      _Pragma("unroll")                                                       \
      for (int cc = 0; cc < 2; ++cc) {                                        \
        gll16(gK[cc], (char*)Ks[NXT] + cc * 4096 + wave * 1024);              \
        gll16(gV[cc], (char*)Vs[NXT] + cc * 4096 + wave * 1024);              \
        gK[cc] += 64 * (size_t)N3_;                                           \
        gV[cc] += 64;                                                         \
      }                                                                       \
    }                                                                         \
    f32x4 s[4] = {zf, zf, zf, zf};                                            \
    __builtin_amdgcn_s_setprio(1);                                            \
    _Pragma("unroll")                                                         \
    for (int kk = 0; kk < 2; ++kk) {                                          \
      _Pragma("unroll")                                                       \
      for (int ni = 0; ni < 4; ++ni) {                                        \
        const int row = ni * 16 + c;                                          \
        v8bf bk = *(const v8bf*)(Ks[CUR] + row * 64 +                         \
                                 ((kk * 32 + g * 8) ^ ((row & 7) << 3)));     \
        s[ni] = __builtin_amdgcn_mfma_f32_16x16x32_bf16(bk, aq[kk], s[ni], 0, 0, 0); \
      }                                                                       \
    }                                                                         \
    __builtin_amdgcn_s_setprio(0);                                            \
    float rsub = 0.f;                                                         \
    v8bf apk[2];                                                              \
    _Pragma("unroll")                                                         \
    for (int ni = 0; ni < 4; ++ni) {                                          \
      float p0 = __builtin_amdgcn_exp2f(s[ni][0]);                            \
      float p1 = __builtin_amdgcn_exp2f(s[ni][1]);                            \
      float p2 = __builtin_amdgcn_exp2f(s[ni][2]);                            \
      float p3 = __builtin_amdgcn_exp2f(s[ni][3]);                            \
      rsub += (p0 + p1) + (p2 + p3);                                          \
      const int kkh = ni >> 1, off = (ni & 1) * 4;                            \
      apk[kkh][off + 0] = (bf16_t)p0;                                         \
      apk[kkh][off + 1] = (bf16_t)p1;                                         \
      apk[kkh][off + 2] = (bf16_t)p2;                                         \
      apk[kkh][off + 3] = (bf16_t)p3;                                         \
    }                                                                         \
    lsum += rsub;                                                             \
    __builtin_amdgcn_s_setprio(1);                                            \
    _Pragma("unroll")                                                         \
    for (int kk = 0; kk < 2; ++kk) {                                          \
      _Pragma("unroll")                                                       \
      for (int ni = 0; ni < 4; ++ni) {                                        \
        const int row = ni * 16 + c;                                          \
        v8bf bv = *(const v8bf*)(Vs[CUR] + row * 64 +                         \
                                 ((kk * 32 + g * 8) ^ ((row & 7) << 3)));     \
        oacc[ni] = __builtin_amdgcn_mfma_f32_16x16x32_bf16(bv, apk[kk], oacc[ni], 0, 0, 0); \
      }                                                                       \
    }                                                                         \
    __builtin_amdgcn_s_setprio(0);                                            \
    __syncthreads();                                                          \
  }

  // NT tiles, unrolled x2 with static buffer indices
  const int NT2 = T_ / (64 * SPLIT * 2);
  for (int kt2 = 0; kt2 < NT2; ++kt2) {
    ATTN_BODY(0, 1, true)
    ATTN_BODY(1, 0, (kt2 < NT2 - 1))
  }
#undef ATTN_BODY

  // epilogue
  lsum += __shfl_xor(lsum, 16);
  lsum += __shfl_xor(lsum, 32);
  const float inv = 1.0f / lsum;
  const int q = qt * 64 + wave * 16 + c;
  if (SPLIT > 1) {
    if (g == 0) lpart[(size_t)z * (B_ * H_ * T_) + (b * H_ + h) * T_ + q] = lsum;
    bf16_t* ob = (bf16_t*)outp + ((size_t)z * M_ * D_ + ((size_t)(b * T_ + q)) * D_ + h * DH_);
    #pragma unroll
    for (int ni = 0; ni < 4; ++ni) {
      v4bf o4 = {(bf16_t)(oacc[ni][0] * inv), (bf16_t)(oacc[ni][1] * inv),
                 (bf16_t)(oacc[ni][2] * inv), (bf16_t)(oacc[ni][3] * inv)};
      *(v4bf*)(ob + ni * 16 + g * 4) = o4;
    }
  } else {
    float* ob = outp + ((size_t)(b * T_ + q)) * D_ + h * DH_;
    #pragma unroll
    for (int ni = 0; ni < 4; ++ni) {
      float4 o4 = {oacc[ni][0] * inv, oacc[ni][1] * inv, oacc[ni][2] * inv, oacc[ni][3] * inv};
      *(float4*)(ob + ni * 16 + g * 4) = o4;
    }
  }
}

extern "C" void kernel_launch(void* const* d_in, const int* in_sizes, int n_in,
                              void* d_out, int out_size, void* d_ws, size_t ws_size,
                              hipStream_t stream) {
  const float* x    = (const float*)d_in[0];
  const float* W    = (const float*)d_in[1];
  const float* bias = (const float*)d_in[2];
  float* out = (float*)d_out;
  char* ws = (char*)d_ws;
  bf16_t* xb    = (bf16_t*)(ws);                 // 4096*768*2   = 6,291,456
  bf16_t* wt    = (bf16_t*)(ws + 6291456);       // 2304*768*2   = 3,538,944
  bf16_t* qkvb  = (bf16_t*)(ws + 9830400);       // 4096*2304*2  = 18,874,368
  bf16_t* vtb   = (bf16_t*)(ws + 28704768);      // 24*64*2048*2 = 6,291,456

  k_conv   <<<dim3(3504),    dim3(256), 0, stream>>>(x, xb, W, wt);
  k_gemm   <<<dim3(576),     dim3(256), 0, stream>>>(xb, wt, bias, qkvb, vtb);
  k_attn<1><<<dim3(768),     dim3(256), 0, stream>>>(qkvb, vtb, out, nullptr);
}